// Round 15
// baseline (3479.504 us; speedup 1.0000x reference)
//
#include <hip/hip_runtime.h>
#include <hip/hip_fp16.h>
#include <hip/hip_cooperative_groups.h>

namespace cg = cooperative_groups;

#define NLAYER 20
#define QLEN 512
#define PAST 512
#define ENDS 1024
#define MAXS 2048
#define DMODEL 896
#define NKV 2
#define NQ 14
#define GQ 7
#define HD 64
#define FF 4864
#define RMSEPS 1e-6f
#define ATT_SCALE 0.125f

typedef _Float16 f16x8 __attribute__((ext_vector_type(8)));
typedef float f32x4 __attribute__((ext_vector_type(4)));
typedef unsigned int u32_;

__device__ __forceinline__ void gld16(const void* g, void* l) {
    __builtin_amdgcn_global_load_lds(
        (const __attribute__((address_space(1))) u32_*)g,
        (__attribute__((address_space(3))) u32_*)l, 16, 0, 0);
}

union SmemU {
    struct { __half As[16384]; __half Bs[16384]; } g; // gemm: 2 bufs x 128rows x 64k
    struct { __half S[16512]; float rowinv[16]; } a;  // attn
    __half Tp[128 * 130];                             // prep f16 transpose buffer
    struct { float red[4]; } r;                       // hfin / rmsfin
};

// ---------------------------------------------------------------------------
// BK=64 gemm staging core (proven r12)
// ---------------------------------------------------------------------------
#define GEMM_STAGE64(A_, lda_, B_, ldb_, Kps_)                                  \
    const int lane = t & 63, wave = t >> 6;                                     \
    const int wm = wave >> 1, wn = wave & 1;                                    \
    const int m0 = by * 128, n0 = bx * 128;                                     \
    const int kb0 = bz * (Kps_);                                                \
    const int la = lane & 15, kg = lane >> 4;                                   \
    const int nIter = (Kps_) >> 6;                                              \
    const int srow = t >> 3;                                                    \
    const int gsw = ((t & 7) ^ (srow & 7)) * 8;                                 \
    f32x4 acc[4][4] = {};                                                       \
    {                                                                           \
        _Pragma("unroll")                                                       \
        for (int q = 0; q < 4; q++) {                                           \
            gld16(&(A_)[(size_t)(m0 + q * 32 + srow) * (lda_) + kb0 + gsw], &As[q * 2048 + t * 8]); \
            gld16(&(B_)[(size_t)(n0 + q * 32 + srow) * (ldb_) + kb0 + gsw], &Bs[q * 2048 + t * 8]); \
        }                                                                       \
    }                                                                           \
    int buf = 0;                                                                \
    for (int kt = 0; kt < nIter; kt++) {                                        \
        __syncthreads();                                                        \
        if (kt + 1 < nIter) {                                                   \
            const int ko = kb0 + (kt + 1) * 64;                                 \
            const int lb = (buf ^ 1) * 8192;                                    \
            _Pragma("unroll")                                                   \
            for (int q = 0; q < 4; q++) {                                       \
                gld16(&(A_)[(size_t)(m0 + q * 32 + srow) * (lda_) + ko + gsw], &As[lb + q * 2048 + t * 8]); \
                gld16(&(B_)[(size_t)(n0 + q * 32 + srow) * (ldb_) + ko + gsw], &Bs[lb + q * 2048 + t * 8]); \
            }                                                                   \
        }                                                                       \
        _Pragma("unroll")                                                       \
        for (int kk = 0; kk < 2; kk++) {                                        \
            f16x8 av[4], bv[4];                                                 \
            const int g = kk * 4 + kg;                                          \
            _Pragma("unroll")                                                   \
            for (int i = 0; i < 4; i++) {                                       \
                const int R = wm * 64 + i * 16 + la;                            \
                av[i] = *(const f16x8*)&As[buf * 8192 + R * 64 + ((g ^ (R & 7)) * 8)]; \
            }                                                                   \
            _Pragma("unroll")                                                   \
            for (int j = 0; j < 4; j++) {                                       \
                const int R = wn * 64 + j * 16 + la;                            \
                bv[j] = *(const f16x8*)&Bs[buf * 8192 + R * 64 + ((g ^ (R & 7)) * 8)]; \
            }                                                                   \
            _Pragma("unroll")                                                   \
            for (int i = 0; i < 4; i++)                                         \
                _Pragma("unroll")                                               \
                for (int j = 0; j < 4; j++)                                     \
                    acc[i][j] = __builtin_amdgcn_mfma_f32_16x16x32_f16(av[i], bv[j], acc[i][j], 0, 0, 0); \
        }                                                                       \
        buf ^= 1;                                                               \
    }                                                                           \
    __syncthreads();

// mode 0: f32 partials per bz (no rs); mode 1: fused silu, rs applied (GU)
__device__ __forceinline__ void gemm_body(
    const __half* __restrict__ A, int lda, const __half* __restrict__ B, int ldb,
    float* __restrict__ outP, __half* __restrict__ actP, const float* __restrict__ rs,
    int N, int Kps, int mode, int bx, int by, int bz, int t, __half* As, __half* Bs)
{
    GEMM_STAGE64(A, lda, B, ldb, Kps)
    const int r0 = m0 + wm * 64 + kg * 4;
    const int c0 = n0 + wn * 64 + la;
    if (mode == 0) {
        float* o = outP + (size_t)bz * QLEN * N;
#pragma unroll
        for (int i = 0; i < 4; i++)
#pragma unroll
            for (int j = 0; j < 4; j++)
#pragma unroll
                for (int r = 0; r < 4; r++)
                    o[(size_t)(r0 + i * 16 + r) * N + c0 + j * 16] = acc[i][j][r];
    } else {
#pragma unroll
        for (int i = 0; i < 4; i++)
#pragma unroll
            for (int j = 0; j < 4; j++)
#pragma unroll
                for (int r = 0; r < 4; r++) {
                    const int row = r0 + i * 16 + r;
                    float v = acc[i][j][r] * rs[row];
                    float other = __shfl_xor(v, 1);
                    if (!(la & 1)) {
                        const int c = c0 + j * 16;
                        float sg = v / (1.f + __expf(-v));
                        actP[(size_t)row * FF + (c >> 1)] = __float2half(sg * other);
                    }
                }
    }
}

// QKV gemm: A = hh (unnormalized f16 h), rs1 applied in epilogue, then
// bias+RoPE+inject+KV-write (non-split K=896; partner col c^32 = acc[i][j^2][r])
__device__ __forceinline__ void gemm_qkv_body(
    const __half* __restrict__ A, const __half* __restrict__ B,
    const float* __restrict__ rs1,
    const float* __restrict__ bqkv, const float* __restrict__ cosb,
    const float* __restrict__ sinb, float inj,
    const float* __restrict__ injk, const float* __restrict__ injv,
    __half* __restrict__ qr, __half* __restrict__ Ka, __half* __restrict__ Vt,
    int layer, int bx, int by, int t, __half* As, __half* Bs)
{
    const int bz = 0;
    GEMM_STAGE64(A, DMODEL, B, DMODEL, 896)
    const int r0 = m0 + wm * 64 + kg * 4;
    const int c0 = n0 + wn * 64 + la;
    const float nrm = 1.f - inj;
#pragma unroll
    for (int i = 0; i < 4; i++)
#pragma unroll
        for (int j = 0; j < 4; j++)
#pragma unroll
            for (int r = 0; r < 4; r++) {
                const int pn = r0 + i * 16 + r;
                const int c = c0 + j * 16;
                const int d = c & 63;
                const float sc = rs1[pn];
                float v = acc[i][j][r] * sc + bqkv[c];
                if (c < 1024) {
                    float pvv = acc[i][j ^ 2][r] * sc + bqkv[c ^ 32];
                    float rot = (d < 32) ? -pvv : pvv;
                    float rv = v * cosb[pn * HD + d] + rot * sinb[pn * HD + d];
                    if (c < 896) {
                        qr[((size_t)(c >> 6) * QLEN + pn) * HD + d] = __float2half(rv);
                    } else {
                        const int kvh = (c - 896) >> 6;
                        float kn = nrm * rv + inj * injk[(((size_t)layer * NKV + kvh) * QLEN + pn) * HD + d];
                        Ka[((size_t)kvh * ENDS + PAST + pn) * HD + d] = __float2half(kn);
                    }
                } else {
                    const int kvh = (c - 1024) >> 6;
                    float vn = nrm * v + inj * injv[(((size_t)layer * NKV + kvh) * QLEN + pn) * HD + d];
                    Vt[((size_t)kvh * HD + d) * ENDS + PAST + pn] = __float2half(vn);
                }
            }
}

// ---------------------------------------------------------------------------
// prep: 128k x 128n tile f32 [K][N] -> f16 [N][K], optional ln fold (W' = diag(ln)W).
// jobs: z0 63 | z1 49 | z2 532 | z3 266 -> 910
// ---------------------------------------------------------------------------
__device__ __forceinline__ void prep_body(
    const float* __restrict__ Wq, const float* __restrict__ Wk, const float* __restrict__ Wv,
    const float* __restrict__ Wo, const float* __restrict__ Wg, const float* __restrict__ Wu,
    const float* __restrict__ Wd, const float* __restrict__ lnv,
    int layer, int z, int bx, int t, __half* Tp, __half* __restrict__ dstW)
{
    const int K = (z == 3) ? FF : DMODEL;
    const int N = (z == 0) ? 1152 : (z == 2) ? 2 * FF : DMODEL;
    const int tilesN = N / 128;
    const int tk = bx / tilesN, tn = bx % tilesN;
    const int k0 = tk * 128, n0 = tn * 128;
    const float* src; int ldn, nc0; int isU = 0;
    if (z == 0) {
        if (n0 < 896)        { src = Wq + (size_t)layer * 896 * 896; ldn = 896; nc0 = n0; }
        else if (n0 < 1024)  { src = Wk + (size_t)layer * 896 * 128; ldn = 128; nc0 = n0 - 896; }
        else                 { src = Wv + (size_t)layer * 896 * 128; ldn = 128; nc0 = n0 - 1024; }
    } else if (z == 1) { src = Wo + (size_t)layer * 896 * 896; ldn = 896; nc0 = n0; }
    else if (z == 2) {
        if (n0 < FF) { src = Wg + (size_t)layer * 896 * FF; ldn = FF; nc0 = n0; }
        else         { src = Wu + (size_t)layer * 896 * FF; ldn = FF; nc0 = n0 - FF; isU = 1; }
    } else { src = Wd + (size_t)layer * FF * 896; ldn = 896; nc0 = n0; }

    __syncthreads();
    const int r8 = t >> 5, cc = (t & 31) * 4;
#pragma unroll
    for (int half = 0; half < 2; half++) {
        float4 v[8];
        float ls[8];
#pragma unroll
        for (int q = 0; q < 8; q++) {
            const int row = half * 64 + q * 8 + r8;
            v[q] = *(const float4*)&src[(size_t)(k0 + row) * ldn + nc0 + cc];
            ls[q] = lnv ? lnv[k0 + row] : 1.f;
        }
#pragma unroll
        for (int q = 0; q < 8; q++) {
            const int row = half * 64 + q * 8 + r8;
            __half2 p0 = __halves2half2(__float2half_rn(v[q].x * ls[q]), __float2half_rn(v[q].y * ls[q]));
            __half2 p1 = __halves2half2(__float2half_rn(v[q].z * ls[q]), __float2half_rn(v[q].w * ls[q]));
            *(__half2*)&Tp[row * 130 + cc] = p0;
            *(__half2*)&Tp[row * 130 + cc + 2] = p1;
        }
    }
    __syncthreads();
    {
        const int nr = t >> 1, kh = (t & 1) * 64;
        const int drow = (z == 2) ? (2 * (nc0 + nr) + isU) : (n0 + nr);
        __half tmp[64];
#pragma unroll
        for (int kk = 0; kk < 64; kk++)
            tmp[kk] = Tp[(kh + kk) * 130 + nr];
        __half* dst = dstW + (size_t)drow * K + k0 + kh;
#pragma unroll
        for (int q = 0; q < 8; q++)
            *(uint4*)(dst + q * 8) = *(const uint4*)&tmp[q * 8];
    }
    __syncthreads();
}

__device__ __forceinline__ void prep_dispatch(
    const float* Wq, const float* Wk, const float* Wv, const float* Wo,
    const float* Wg, const float* Wu, const float* Wd,
    const float* bq, const float* bk, const float* bv,
    const float* ln1, const float* ln2,
    int layer, int j, int t, __half* Tp,
    __half* wq, __half* wo, __half* wgu, __half* wd, float* bqkv)
{
    int z; __half* dst; int bx = j; const float* lnv = nullptr;
    if (j < 63)         { z = 0; dst = wq;  lnv = ln1 + (size_t)layer * 896; }
    else if (j < 112)   { z = 1; dst = wo;  bx -= 63; }
    else if (j < 644)   { z = 2; dst = wgu; bx -= 112; lnv = ln2 + (size_t)layer * 896; }
    else                { z = 3; dst = wd;  bx -= 644; }
    prep_body(Wq, Wk, Wv, Wo, Wg, Wu, Wd, lnv, layer, z, bx, t, Tp, dst);
    if (z == 0 && bx == 0) {
        for (int i = t; i < 1152; i += 256) {
            float b = (i < 896) ? bq[(size_t)layer * 896 + i]
                    : (i < 1024) ? bk[(size_t)layer * 128 + i - 896]
                                 : bv[(size_t)layer * 128 + i - 1024];
            bqkv[i] = b;
        }
    }
}

// past-cache copy (f32 cache, proven r5)
__device__ __forceinline__ void cache_copy_body(
    const float* __restrict__ kc32, const float* __restrict__ vc32, int layer,
    __half* __restrict__ Ka, __half* __restrict__ Vt, int p, int lt)
{
    const int kvh = lt >> 6, d = lt & 63;
    const size_t idx = (((size_t)layer * NKV + kvh) * MAXS + p) * HD + d;
    Ka[((size_t)kvh * ENDS + p) * HD + d] = __float2half(kc32[idx]);
    Vt[((size_t)kvh * HD + d) * ENDS + p] = __float2half(vc32[idx]);
}

__device__ __forceinline__ int sswz(int row, int col) {
    return row * 1032 + (col ^ ((row & 7) << 3));
}

__device__ __forceinline__ void attn_body(
    const __half* __restrict__ qr, const __half* __restrict__ Ka,
    const __half* __restrict__ Vt, const float* __restrict__ mask,
    __half* __restrict__ ob, int q0, int h, int t, __half* S, float* rowinv)
{
    const int kv = h / GQ;
    const int lane = t & 63, w = t >> 6;
    const int la = lane & 15, kg = lane >> 4;

    const f16x8* qp = (const f16x8*)&qr[((size_t)h * QLEN + q0 + la) * HD + kg * 8];
    const f16x8 qa0 = qp[0], qa1 = qp[4];
    __syncthreads();

    for (int kb = 0; kb < 256; kb += 16) {
        const int key = w * 256 + kb + la;
        const f16x8* kp = (const f16x8*)&Ka[((size_t)kv * ENDS + key) * HD + kg * 8];
        f32x4 s4 = {0.f, 0.f, 0.f, 0.f};
        s4 = __builtin_amdgcn_mfma_f32_16x16x32_f16(qa0, kp[0], s4, 0, 0, 0);
        s4 = __builtin_amdgcn_mfma_f32_16x16x32_f16(qa1, kp[4], s4, 0, 0, 0);
#pragma unroll
        for (int r = 0; r < 4; r++) {
            const int row = kg * 4 + r;
            float sv = s4[r] * ATT_SCALE + mask[(size_t)(q0 + row) * ENDS + key];
            S[sswz(row, key)] = __float2half(sv);
        }
    }
    __syncthreads();
    {
        const int row = w * 4 + kg;
        float mx = -1e30f;
        for (int j = 0; j < 64; j++)
            mx = fmaxf(mx, __half2float(S[sswz(row, la + 16 * j)]));
        for (int o = 1; o < 16; o <<= 1) mx = fmaxf(mx, __shfl_xor(mx, o));
        float sum = 0.f;
        for (int j = 0; j < 64; j++) {
            const int idx = sswz(row, la + 16 * j);
            float e = __expf(__half2float(S[idx]) - mx);
            S[idx] = __float2half(e);
            sum += e;
        }
        for (int o = 1; o < 16; o <<= 1) sum += __shfl_xor(sum, o);
        if (la == 0) rowinv[row] = 1.f / sum;
    }
    __syncthreads();
    {
        const int d = 16 * w + la;
        const __half* vrow = &Vt[((size_t)kv * HD + d) * ENDS];
        f32x4 acc = {0.f, 0.f, 0.f, 0.f};
        for (int ks = 0; ks < ENDS; ks += 32) {
            f16x8 pa = *(const f16x8*)&S[sswz(la, ks + kg * 8)];
            f16x8 vb = *(const f16x8*)&vrow[ks + kg * 8];
            acc = __builtin_amdgcn_mfma_f32_16x16x32_f16(pa, vb, acc, 0, 0, 0);
        }
#pragma unroll
        for (int r = 0; r < 4; r++) {
            const int qrow = kg * 4 + r;
            ob[(size_t)(q0 + qrow) * (NQ * HD) + h * HD + d] =
                __float2half(acc[r] * rowinv[qrow]);
        }
    }
    __syncthreads();
}

// h-finalize: h += sum(parts); hh = f16(h); rs[m] = rsqrt(mean(h^2)+eps)
__device__ __forceinline__ void hfin_body(
    float* __restrict__ h, const float* __restrict__ parts, int nparts,
    __half* __restrict__ hh, float* __restrict__ rs, int m, int t, float* red)
{
    float loc[4];
    float ss = 0.f;
    int r = 0;
    for (int i = t; i < DMODEL; i += 256, r++) {
        float x = h[(size_t)m * DMODEL + i];
        for (int s = 0; s < nparts; s++)
            x += parts[(size_t)s * QLEN * DMODEL + (size_t)m * DMODEL + i];
        loc[r] = x;
        if (nparts) h[(size_t)m * DMODEL + i] = x;
        ss += x * x;
    }
    for (int o = 32; o; o >>= 1) ss += __shfl_xor(ss, o);
    if ((t & 63) == 0) red[t >> 6] = ss;
    __syncthreads();
    if (t == 0) rs[m] = rsqrtf((red[0] + red[1] + red[2] + red[3]) / (float)DMODEL + RMSEPS);
    r = 0;
    for (int i = t; i < DMODEL; i += 256, r++)
        hh[(size_t)m * DMODEL + i] = __float2half(loc[r]);
    __syncthreads();
}

// final rms (output f32): out = rmsnorm(h + parts) * w
__device__ __forceinline__ void rmsfin_body(
    float* __restrict__ h, const float* __restrict__ parts, int nparts,
    const float* __restrict__ w, float* __restrict__ out, int m, int t, float* red)
{
    float loc[4];
    float ss = 0.f;
    int r = 0;
    for (int i = t; i < DMODEL; i += 256, r++) {
        float x = h[(size_t)m * DMODEL + i];
        for (int s = 0; s < nparts; s++)
            x += parts[(size_t)s * QLEN * DMODEL + (size_t)m * DMODEL + i];
        loc[r] = x;
        ss += x * x;
    }
    for (int o = 32; o; o >>= 1) ss += __shfl_xor(ss, o);
    if ((t & 63) == 0) red[t >> 6] = ss;
    __syncthreads();
    float rsv = rsqrtf((red[0] + red[1] + red[2] + red[3]) / (float)DMODEL + RMSEPS);
    r = 0;
    for (int i = t; i < DMODEL; i += 256, r++)
        out[(size_t)m * DMODEL + i] = loc[r] * rsv * w[i];
    __syncthreads();
}

// ---------------------------------------------------------------------------
// mega kernel: 7 phases/layer; ln folded; rs epilogues; SHORT-K splits
// (O split-7 -> 2 iters, D split-19 -> 4 iters; critical path, not traffic).
// ---------------------------------------------------------------------------
struct P22 {
    const float *hidden, *cosb, *sinb, *mask, *injm, *injk, *injv, *kc32, *vc32;
    const float *Wq, *bq, *Wk, *bk, *Wv, *bv, *Wo, *ln1, *ln2, *Wg, *Wu, *Wd, *finw;
    float *h; __half *hh, *qr, *Ka, *Vt, *ob, *act; float *BIGR;
    float *rs1, *rs2;
    float *bqkv0, *bqkv1;
    __half *wq0, *wo0, *wgu0, *wd0, *wq1, *wo1, *wgu1, *wd1;
    float *outF;
};

// prep chunks (sum = 910)
#define PC_B 270
#define PC_C 60
#define PC_D 200
#define PC_F 208
#define PC_G 172
#define PB_B 0
#define PB_C 270
#define PB_D 330
#define PB_F 530
#define PB_G 738

__global__ __launch_bounds__(256) void mega_kernel(P22 P)
{
    __shared__ SmemU sm;
    cg::grid_group gg = cg::this_grid();
    const int nb = gridDim.x, bid = blockIdx.x, t = threadIdx.x;
    const float inj = P.injm[0];

    for (int j = bid; j < 1792; j += nb) {
        int i = j * 256 + t;
        if (i < QLEN * DMODEL) P.h[i] = P.hidden[i];
    }
    for (int j = bid; j < 256; j += nb)
        cache_copy_body(P.kc32, P.vc32, 0, P.Ka, P.Vt, j * 2 + (t >> 7), t & 127);
    for (int j = bid; j < 910; j += nb)
        prep_dispatch(P.Wq, P.Wk, P.Wv, P.Wo, P.Wg, P.Wu, P.Wd, P.bq, P.bk, P.bv,
                      P.ln1, P.ln2, 0, j, t, sm.Tp, P.wq0, P.wo0, P.wgu0, P.wd0, P.bqkv0);
    gg.sync();

    for (int l = 0; l < NLAYER; l++) {
        const int pb = l & 1;
        const __half* wq  = pb ? P.wq1  : P.wq0;
        const __half* wo  = pb ? P.wo1  : P.wo0;
        const __half* wgu = pb ? P.wgu1 : P.wgu0;
        const __half* wd  = pb ? P.wd1  : P.wd0;
        const float*  bqk = pb ? P.bqkv1 : P.bqkv0;
        const bool hasN = (l + 1 < NLAYER);
        __half* nwq  = pb ? P.wq0  : P.wq1;
        __half* nwo  = pb ? P.wo0  : P.wo1;
        __half* nwgu = pb ? P.wgu0 : P.wgu1;
        __half* nwd  = pb ? P.wd0  : P.wd1;
        float*  nbq  = pb ? P.bqkv0 : P.bqkv1;
        #define PREPN(idx) prep_dispatch(P.Wq, P.Wk, P.Wv, P.Wo, P.Wg, P.Wu, P.Wd, \
            P.bq, P.bk, P.bv, P.ln1, P.ln2, l + 1, (idx), t, sm.Tp, nwq, nwo, nwgu, nwd, nbq)

        // A: h-finalize-1 (h += 19 D-partials; hh; rs1)
        for (int j = bid; j < QLEN; j += nb)
            hfin_body(P.h, l ? P.BIGR : nullptr, l ? 19 : 0, P.hh, P.rs1, j, t, sm.r.red);
        gg.sync();

        // B: QKV gemm fused rope (36, 14 iters) + prep
        for (int j = bid; j < 36 + (hasN ? PC_B : 0); j += nb) {
            if (j < 36)
                gemm_qkv_body(P.hh, wq, P.rs1, bqk, P.cosb, P.sinb, inj, P.injk, P.injv,
                              P.qr, P.Ka, P.Vt, l, j % 9, j / 9, t, sm.g.As, sm.g.Bs);
            else PREPN(PB_B + j - 36);
        }
        gg.sync();

        // C: attention (448) + prep
        for (int j = bid; j < 448 + (hasN ? PC_C : 0); j += nb) {
            if (j < 448)
                attn_body(P.qr, P.Ka, P.Vt, P.mask, P.ob, (j & 31) * 16, j >> 5, t,
                          sm.a.S, sm.a.rowinv);
            else PREPN(PB_C + j - 448);
        }
        gg.sync();

        // D: O gemm split-7 (196, 2 iters) + cache_copy(l+1) (256) + prep
        for (int j = bid; j < 452 + (hasN ? PC_D : 0); j += nb) {
            if (j < 196) {
                int z = j / 28, r = j % 28;
                gemm_body(P.ob, DMODEL, wo, DMODEL, P.BIGR, nullptr, nullptr,
                          DMODEL, 128, 0, r % 7, r / 7, z, t, sm.g.As, sm.g.Bs);
            } else if (j < 452) {
                if (hasN) cache_copy_body(P.kc32, P.vc32, l + 1, P.Ka, P.Vt,
                                          (j - 196) * 2 + (t >> 7), t & 127);
            } else PREPN(PB_D + j - 452);
        }
        gg.sync();

        // E: h-finalize-2 (h += 7 O-partials; hh; rs2)
        for (int j = bid; j < QLEN; j += nb)
            hfin_body(P.h, P.BIGR, 7, P.hh, P.rs2, j, t, sm.r.red);
        gg.sync();

        // F: GU gemm fused silu+rs2 (304, 14 iters) + prep
        for (int j = bid; j < 304 + (hasN ? PC_F : 0); j += nb) {
            if (j < 304)
                gemm_body(P.hh, DMODEL, wgu, DMODEL, nullptr, P.act, P.rs2,
                          2 * FF, 896, 1, j % 76, j / 76, 0, t, sm.g.As, sm.g.Bs);
            else PREPN(PB_F + j - 304);
        }
        gg.sync();

        // G: D gemm split-19 (532, 4 iters) + prep
        for (int j = bid; j < 532 + (hasN ? PC_G : 0); j += nb) {
            if (j < 532) {
                int z = j / 28, r = j % 28;
                gemm_body(P.act, FF, wd, FF, P.BIGR, nullptr, nullptr,
                          DMODEL, 256, 0, r % 7, r / 7, z, t, sm.g.As, sm.g.Bs);
            } else PREPN(PB_G + j - 532);
        }
        gg.sync();
        #undef PREPN
    }
    for (int j = bid; j < QLEN; j += nb)
        rmsfin_body(P.h, P.BIGR, 19, P.finw, P.outF, j, t, sm.r.red);
}

// ---------------------------------------------------------------------------
// legacy fallback wrappers (same folded scheme, separate launches)
// ---------------------------------------------------------------------------
__global__ __launch_bounds__(256) void init_kernel(
    const float* __restrict__ hidden, float* __restrict__ h)
{
    const int idx = blockIdx.x * 256 + threadIdx.x;
    if (idx < QLEN * DMODEL) h[idx] = hidden[idx];
}

__global__ __launch_bounds__(256) void prep_all(
    const float* Wq, const float* Wk, const float* Wv, const float* Wo,
    const float* Wg, const float* Wu, const float* Wd,
    const float* bq, const float* bk, const float* bv,
    const float* ln1, const float* ln2, int layer,
    __half* wqkv, __half* wo, __half* wgu, __half* wd, float* bqkv)
{
    __shared__ __half Tp[128 * 130];
    prep_dispatch(Wq, Wk, Wv, Wo, Wg, Wu, Wd, bq, bk, bv, ln1, ln2, layer,
                  blockIdx.x, threadIdx.x, Tp, wqkv, wo, wgu, wd, bqkv);
}

__global__ __launch_bounds__(256) void gemm128(
    const __half* A, int lda, const __half* B, int ldb,
    float* outP, __half* actP, const float* rs, int N, int Kps, int mode)
{
    __shared__ SmemU sm;
    gemm_body(A, lda, B, ldb, outP, actP, rs, N, Kps, mode,
              blockIdx.x, blockIdx.y, blockIdx.z, threadIdx.x, sm.g.As, sm.g.Bs);
}

__global__ __launch_bounds__(256) void gemm_qkv(
    const __half* A, const __half* B, const float* rs1, const float* bqkv,
    const float* cosb, const float* sinb, const float* injm,
    const float* injk, const float* injv,
    __half* qr, __half* Ka, __half* Vt, int layer)
{
    __shared__ SmemU sm;
    gemm_qkv_body(A, B, rs1, bqkv, cosb, sinb, injm[0], injk, injv,
                  qr, Ka, Vt, layer, blockIdx.x, blockIdx.y, threadIdx.x,
                  sm.g.As, sm.g.Bs);
}

__global__ __launch_bounds__(128) void cache_copy_kernel(
    const float* kc32, const float* vc32, int layer, __half* Ka, __half* Vt)
{
    cache_copy_body(kc32, vc32, layer, Ka, Vt, blockIdx.x, threadIdx.x);
}

__global__ __launch_bounds__(256) void attn_mfma(
    const __half* qr, const __half* Ka, const __half* Vt, const float* mask, __half* ob)
{
    __shared__ SmemU sm;
    attn_body(qr, Ka, Vt, mask, ob, blockIdx.x * 16, blockIdx.y, threadIdx.x,
              sm.a.S, sm.a.rowinv);
}

__global__ __launch_bounds__(256) void hfin_kernel(
    float* h, const float* parts, int nparts, __half* hh, float* rs)
{
    __shared__ float red[4];
    hfin_body(h, parts, nparts, hh, rs, blockIdx.x, threadIdx.x, red);
}

__global__ __launch_bounds__(256) void rmsfin_kernel(
    float* h, const float* parts, int nparts, const float* w, float* out)
{
    __shared__ float red[4];
    rmsfin_body(h, parts, nparts, w, out, blockIdx.x, threadIdx.x, red);
}

// ---------------------------------------------------------------------------
extern "C" void kernel_launch(void* const* d_in, const int* in_sizes, int n_in,
                              void* d_out, int out_size, void* d_ws, size_t ws_size,
                              hipStream_t stream)
{
    const float*  hidden = (const float*)d_in[0];
    const float*  cosb   = (const float*)d_in[1];
    const float*  sinb   = (const float*)d_in[2];
    const float*  mask   = (const float*)d_in[3];
    const float*  injm   = (const float*)d_in[4];
    const float*  injk   = (const float*)d_in[5];
    const float*  injv   = (const float*)d_in[6];
    const float*  kc32   = (const float*)d_in[7];   // f32 (harness upcast, proven r5)
    const float*  vc32   = (const float*)d_in[8];
    const float*  Wq     = (const float*)d_in[9];
    const float*  bq     = (const float*)d_in[10];
    const float*  Wk     = (const float*)d_in[11];
    const float*  bk     = (const float*)d_in[12];
    const float*  Wv     = (const float*)d_in[13];
    const float*  bv     = (const float*)d_in[14];
    const float*  Wo     = (const float*)d_in[15];
    const float*  ln1    = (const float*)d_in[16];
    const float*  ln2    = (const float*)d_in[17];
    const float*  Wg     = (const float*)d_in[18];
    const float*  Wu     = (const float*)d_in[19];
    const float*  Wd     = (const float*)d_in[20];
    const float*  finw   = (const float*)d_in[21];

    bool size_ok = (n_in == 22) &&
        in_sizes[0] == 458752 && in_sizes[1] == 32768 && in_sizes[3] == 524288 &&
        in_sizes[4] == 1 && in_sizes[5] == 1310720 && in_sizes[7] == 5242880 &&
        in_sizes[9] == 16056320 && in_sizes[10] == 17920 && in_sizes[11] == 2293760 &&
        in_sizes[15] == 16056320 && in_sizes[16] == 17920 && in_sizes[18] == 87162880 &&
        in_sizes[20] == 87162880 && in_sizes[21] == 896;
    if (!size_ok) { hipMemsetAsync(d_out, 0x42, (size_t)out_size * 4, stream); return; }

    char* ws = (char*)d_ws;
    size_t off = 0;
    auto alloc = [&](size_t bytes) { void* p = ws + off; off += (bytes + 255) & ~255ull; return p; };
    float*  bqkv0 = (float*)alloc(1152 * 4);
    float*  bqkv1 = (float*)alloc(1152 * 4);
    float*  rs1   = (float*)alloc(QLEN * 4);
    float*  rs2   = (float*)alloc(QLEN * 4);
    float*  h     = (float*)alloc((size_t)QLEN * DMODEL * 4);
    __half* hh    = (__half*)alloc((size_t)QLEN * DMODEL * 2);
    __half* qr    = (__half*)alloc((size_t)NQ * QLEN * HD * 2);
    __half* Ka    = (__half*)alloc((size_t)NKV * ENDS * HD * 2);
    __half* Vt    = (__half*)alloc((size_t)NKV * ENDS * HD * 2);
    __half* ob    = (__half*)alloc((size_t)QLEN * NQ * HD * 2);
    __half* act   = (__half*)alloc((size_t)QLEN * FF * 2);
    float*  BIGR  = (float*)alloc(19ull * QLEN * DMODEL * 4);
    __half* wq0   = (__half*)alloc(2064384);
    __half* wo0   = (__half*)alloc(1605632);
    __half* wgu0  = (__half*)alloc(17432576);
    __half* wd0   = (__half*)alloc(8716288);
    const size_t NEED_LEGACY = off;
    __half* wq1   = (__half*)alloc(2064384);
    __half* wo1   = (__half*)alloc(1605632);
    __half* wgu1  = (__half*)alloc(17432576);
    __half* wd1   = (__half*)alloc(8716288);
    const size_t NEED_MEGA = off;

    if (ws_size < NEED_LEGACY) {
        hipMemsetAsync(d_out, 0, (size_t)out_size * 4, stream);
        return;
    }

    bool mega_ok = (ws_size >= NEED_MEGA);
    if (mega_ok) {
        int maxB = 0;
        hipError_t e = hipOccupancyMaxActiveBlocksPerMultiprocessor(
            &maxB, reinterpret_cast<const void*>(&mega_kernel), 256, 0);
        if (e != hipSuccess || maxB < 1) mega_ok = false;
        if (mega_ok) {
            int grid = maxB * 256;
            if (grid > 512) grid = 512;
            P22 Pv = { hidden, cosb, sinb, mask, injm, injk, injv, kc32, vc32,
                       Wq, bq, Wk, bk, Wv, bv, Wo, ln1, ln2, Wg, Wu, Wd, finw,
                       h, hh, qr, Ka, Vt, ob, act, BIGR, rs1, rs2, bqkv0, bqkv1,
                       wq0, wo0, wgu0, wd0, wq1, wo1, wgu1, wd1, (float*)d_out };
            void* args[] = { (void*)&Pv };
            hipError_t le = hipLaunchCooperativeKernel(
                reinterpret_cast<const void*>(&mega_kernel),
                dim3(grid), dim3(256), args, 0, stream);
            if (le == hipSuccess) return;
            mega_ok = false;
        }
    }

    // ---- legacy path (same folded scheme, separate launches) ----
    init_kernel<<<1792, 256, 0, stream>>>(hidden, h);
    for (int l = 0; l < NLAYER; l++) {
        prep_all<<<910, 256, 0, stream>>>(Wq, Wk, Wv, Wo, Wg, Wu, Wd, bq, bk, bv,
                                          ln1, ln2, l, wq0, wo0, wgu0, wd0, bqkv0);
        hfin_kernel<<<QLEN, 256, 0, stream>>>(h, l ? BIGR : nullptr, l ? 19 : 0, hh, rs1);
        cache_copy_kernel<<<PAST, 128, 0, stream>>>(kc32, vc32, l, Ka, Vt);
        gemm_qkv<<<dim3(9, 4), 256, 0, stream>>>(hh, wq0, rs1, bqkv0, cosb, sinb,
                                                 injm, injk, injv, qr, Ka, Vt, l);
        attn_mfma<<<dim3(32, 14), 256, 0, stream>>>(qr, Ka, Vt, mask, ob);
        gemm128<<<dim3(7, 4, 7), 256, 0, stream>>>(ob, DMODEL, wo0, DMODEL, BIGR,
                                                   nullptr, nullptr, DMODEL, 128, 0);
        hfin_kernel<<<QLEN, 256, 0, stream>>>(h, BIGR, 7, hh, rs2);
        gemm128<<<dim3(76, 4, 1), 256, 0, stream>>>(hh, DMODEL, wgu0, DMODEL, nullptr,
                                                    act, rs2, 2 * FF, 896, 1);
        gemm128<<<dim3(7, 4, 19), 256, 0, stream>>>(act, FF, wd0, FF, BIGR,
                                                    nullptr, nullptr, DMODEL, 256, 0);
    }
    rmsfin_kernel<<<QLEN, 256, 0, stream>>>(h, BIGR, 19, finw, (float*)d_out);
}

// Round 16
// 2765.222 us; speedup vs baseline: 1.2583x; 1.2583x over previous
//
#include <hip/hip_runtime.h>
#include <hip/hip_fp16.h>
#include <hip/hip_cooperative_groups.h>

namespace cg = cooperative_groups;

#define NLAYER 20
#define QLEN 512
#define PAST 512
#define ENDS 1024
#define MAXS 2048
#define DMODEL 896
#define NKV 2
#define NQ 14
#define GQ 7
#define HD 64
#define FF 4864
#define RMSEPS 1e-6f
#define ATT_SCALE 0.125f

typedef _Float16 f16x8 __attribute__((ext_vector_type(8)));
typedef float f32x4 __attribute__((ext_vector_type(4)));
typedef unsigned int u32_;

__device__ __forceinline__ void gld16(const void* g, void* l) {
    __builtin_amdgcn_global_load_lds(
        (const __attribute__((address_space(1))) u32_*)g,
        (__attribute__((address_space(3))) u32_*)l, 16, 0, 0);
}

union SmemU {
    struct { __half As[16384]; __half Bs[16384]; } g; // gemm: 2 bufs x 128rows x 64k
    struct { __half S[16512]; float rowinv[16]; } a;  // attn
    struct { float T[32][129]; } p;                   // prep
    struct { float red[4]; } r;                       // rms
};

// ---------------------------------------------------------------------------
// BK=64 gemm staging core. XOR-swizzle on 16B granules within each 128B row:
// LDS holds global granule (g ^ (row&7)) at linear granule g; reads invert.
// Stage: round q covers rows q*32+(t>>3); LDS dest = base + t*16 (linear, gld16-legal).
// ---------------------------------------------------------------------------
#define GEMM_STAGE64(A_, lda_, B_, ldb_, Kps_)                                  \
    const int lane = t & 63, wave = t >> 6;                                     \
    const int wm = wave >> 1, wn = wave & 1;                                    \
    const int m0 = by * 128, n0 = bx * 128;                                     \
    const int kb0 = bz * (Kps_);                                                \
    const int la = lane & 15, kg = lane >> 4;                                   \
    const int nIter = (Kps_) >> 6;                                              \
    const int srow = t >> 3;                                                    \
    const int gsw = ((t & 7) ^ (srow & 7)) * 8;                                 \
    f32x4 acc[4][4] = {};                                                       \
    {                                                                           \
        _Pragma("unroll")                                                       \
        for (int q = 0; q < 4; q++) {                                           \
            gld16(&(A_)[(size_t)(m0 + q * 32 + srow) * (lda_) + kb0 + gsw], &As[q * 2048 + t * 8]); \
            gld16(&(B_)[(size_t)(n0 + q * 32 + srow) * (ldb_) + kb0 + gsw], &Bs[q * 2048 + t * 8]); \
        }                                                                       \
    }                                                                           \
    int buf = 0;                                                                \
    for (int kt = 0; kt < nIter; kt++) {                                        \
        __syncthreads();                                                        \
        if (kt + 1 < nIter) {                                                   \
            const int ko = kb0 + (kt + 1) * 64;                                 \
            const int lb = (buf ^ 1) * 8192;                                    \
            _Pragma("unroll")                                                   \
            for (int q = 0; q < 4; q++) {                                       \
                gld16(&(A_)[(size_t)(m0 + q * 32 + srow) * (lda_) + ko + gsw], &As[lb + q * 2048 + t * 8]); \
                gld16(&(B_)[(size_t)(n0 + q * 32 + srow) * (ldb_) + ko + gsw], &Bs[lb + q * 2048 + t * 8]); \
            }                                                                   \
        }                                                                       \
        _Pragma("unroll")                                                       \
        for (int kk = 0; kk < 2; kk++) {                                        \
            f16x8 av[4], bv[4];                                                 \
            const int g = kk * 4 + kg;                                          \
            _Pragma("unroll")                                                   \
            for (int i = 0; i < 4; i++) {                                       \
                const int R = wm * 64 + i * 16 + la;                            \
                av[i] = *(const f16x8*)&As[buf * 8192 + R * 64 + ((g ^ (R & 7)) * 8)]; \
            }                                                                   \
            _Pragma("unroll")                                                   \
            for (int j = 0; j < 4; j++) {                                       \
                const int R = wn * 64 + j * 16 + la;                            \
                bv[j] = *(const f16x8*)&Bs[buf * 8192 + R * 64 + ((g ^ (R & 7)) * 8)]; \
            }                                                                   \
            _Pragma("unroll")                                                   \
            for (int i = 0; i < 4; i++)                                         \
                _Pragma("unroll")                                               \
                for (int j = 0; j < 4; j++)                                     \
                    acc[i][j] = __builtin_amdgcn_mfma_f32_16x16x32_f16(av[i], bv[j], acc[i][j], 0, 0, 0); \
        }                                                                       \
        buf ^= 1;                                                               \
    }                                                                           \
    __syncthreads();

// mode 0: f32 partials per bz; mode 1: fused silu (GU interleaved rows)
__device__ __forceinline__ void gemm_body(
    const __half* __restrict__ A, int lda, const __half* __restrict__ B, int ldb,
    float* __restrict__ outP, __half* __restrict__ actP, int N, int Kps, int mode,
    int bx, int by, int bz, int t, __half* As, __half* Bs)
{
    GEMM_STAGE64(A, lda, B, ldb, Kps)
    const int r0 = m0 + wm * 64 + kg * 4;
    const int c0 = n0 + wn * 64 + la;
    if (mode == 0) {
        float* o = outP + (size_t)bz * QLEN * N;
#pragma unroll
        for (int i = 0; i < 4; i++)
#pragma unroll
            for (int j = 0; j < 4; j++)
#pragma unroll
                for (int r = 0; r < 4; r++)
                    o[(size_t)(r0 + i * 16 + r) * N + c0 + j * 16] = acc[i][j][r];
    } else {
#pragma unroll
        for (int i = 0; i < 4; i++)
#pragma unroll
            for (int j = 0; j < 4; j++)
#pragma unroll
                for (int r = 0; r < 4; r++) {
                    float v = acc[i][j][r];
                    float other = __shfl_xor(v, 1);
                    if (!(la & 1)) {
                        const int c = c0 + j * 16;
                        const int row = r0 + i * 16 + r;
                        float sg = v / (1.f + __expf(-v));
                        actP[(size_t)row * FF + (c >> 1)] = __float2half(sg * other);
                    }
                }
    }
}

// QKV gemm, fused bias+RoPE+inject+KV-write (non-split K=896; partner col = c^32
// lives in acc[i][j^2][r], thread-local).
__device__ __forceinline__ void gemm_qkv_body(
    const __half* __restrict__ A, const __half* __restrict__ B,
    const float* __restrict__ bqkv, const float* __restrict__ cosb,
    const float* __restrict__ sinb, float inj,
    const float* __restrict__ injk, const float* __restrict__ injv,
    __half* __restrict__ qr, __half* __restrict__ Ka, __half* __restrict__ Vt,
    int layer, int bx, int by, int t, __half* As, __half* Bs)
{
    const int bz = 0;
    GEMM_STAGE64(A, DMODEL, B, DMODEL, 896)
    const int r0 = m0 + wm * 64 + kg * 4;
    const int c0 = n0 + wn * 64 + la;
    const float nrm = 1.f - inj;
#pragma unroll
    for (int i = 0; i < 4; i++)
#pragma unroll
        for (int j = 0; j < 4; j++)
#pragma unroll
            for (int r = 0; r < 4; r++) {
                const int pn = r0 + i * 16 + r;
                const int c = c0 + j * 16;
                const int d = c & 63;
                float v = acc[i][j][r] + bqkv[c];
                if (c < 1024) {
                    float pvv = acc[i][j ^ 2][r] + bqkv[c ^ 32];
                    float rot = (d < 32) ? -pvv : pvv;
                    float rv = v * cosb[pn * HD + d] + rot * sinb[pn * HD + d];
                    if (c < 896) {
                        qr[((size_t)(c >> 6) * QLEN + pn) * HD + d] = __float2half(rv);
                    } else {
                        const int kvh = (c - 896) >> 6;
                        float kn = nrm * rv + inj * injk[(((size_t)layer * NKV + kvh) * QLEN + pn) * HD + d];
                        Ka[((size_t)kvh * ENDS + PAST + pn) * HD + d] = __float2half(kn);
                    }
                } else {
                    const int kvh = (c - 1024) >> 6;
                    float vn = nrm * v + inj * injv[(((size_t)layer * NKV + kvh) * QLEN + pn) * HD + d];
                    Vt[((size_t)kvh * HD + d) * ENDS + PAST + pn] = __float2half(vn);
                }
            }
}

// ---------------------------------------------------------------------------
// prep: 32k x 128n tile f32 [K][N] -> f16 [N][K]; 3640 jobs total
// z: 0=QKV(896,1152) 1=O(896,896) 2=GU(896,9728 interleaved) 3=D(4864,896)
// ---------------------------------------------------------------------------
__device__ __forceinline__ void prep_body(
    const float* __restrict__ Wq, const float* __restrict__ Wk, const float* __restrict__ Wv,
    const float* __restrict__ Wo, const float* __restrict__ Wg, const float* __restrict__ Wu,
    const float* __restrict__ Wd, int layer, int z, int bx, int t, float (*T)[129],
    __half* __restrict__ dstW)
{
    const int K = (z == 3) ? FF : DMODEL;
    const int N = (z == 0) ? 1152 : (z == 2) ? 2 * FF : DMODEL;
    const int tilesN = N / 128;
    const int tk = bx / tilesN, tn = bx % tilesN;
    const int k0 = tk * 32, n0 = tn * 128;
    const float* src; int ldn, nc0; int isU = 0;
    if (z == 0) {
        if (n0 < 896)        { src = Wq + (size_t)layer * 896 * 896; ldn = 896; nc0 = n0; }
        else if (n0 < 1024)  { src = Wk + (size_t)layer * 896 * 128; ldn = 128; nc0 = n0 - 896; }
        else                 { src = Wv + (size_t)layer * 896 * 128; ldn = 128; nc0 = n0 - 1024; }
    } else if (z == 1) { src = Wo + (size_t)layer * 896 * 896; ldn = 896; nc0 = n0; }
    else if (z == 2) {
        if (n0 < FF) { src = Wg + (size_t)layer * 896 * FF; ldn = FF; nc0 = n0; }
        else         { src = Wu + (size_t)layer * 896 * FF; ldn = FF; nc0 = n0 - FF; isU = 1; }
    } else { src = Wd + (size_t)layer * FF * 896; ldn = 896; nc0 = n0; }

    __syncthreads();
    {
        const int r = t >> 3, cb = (t & 7) * 16;
        const float* s = &src[(size_t)(k0 + r) * ldn + nc0 + cb];
#pragma unroll
        for (int q = 0; q < 4; q++) {
            float4 v = *(const float4*)&s[q * 4];
            T[r][cb + q * 4 + 0] = v.x; T[r][cb + q * 4 + 1] = v.y;
            T[r][cb + q * 4 + 2] = v.z; T[r][cb + q * 4 + 3] = v.w;
        }
    }
    __syncthreads();
    {
        const int nr = t >> 1, kh = (t & 1) * 16;
        const int drow = (z == 2) ? (2 * (nc0 + nr) + isU) : (n0 + nr);
        __half tmp[16];
#pragma unroll
        for (int kk = 0; kk < 16; kk++)
            tmp[kk] = __float2half_rn(T[kh + kk][nr]);
        __half* dst = dstW + (size_t)drow * K + k0 + kh;
        *(uint4*)dst = *(const uint4*)&tmp[0];
        *(uint4*)(dst + 8) = *(const uint4*)&tmp[8];
    }
    __syncthreads();
}

__device__ __forceinline__ void prep_dispatch(
    const float* Wq, const float* Wk, const float* Wv, const float* Wo,
    const float* Wg, const float* Wu, const float* Wd,
    const float* bq, const float* bk, const float* bv,
    int layer, int j, int t, float (*T)[129],
    __half* wq, __half* wo, __half* wgu, __half* wd, float* bqkv)
{
    int z; __half* dst; int bx = j;
    if (j < 252)        { z = 0; dst = wq; }
    else if (j < 448)   { z = 1; dst = wo;  bx -= 252; }
    else if (j < 2576)  { z = 2; dst = wgu; bx -= 448; }
    else                { z = 3; dst = wd;  bx -= 2576; }
    prep_body(Wq, Wk, Wv, Wo, Wg, Wu, Wd, layer, z, bx, t, T, dst);
    if (z == 0 && bx == 0) {
        for (int i = t; i < 1152; i += 256) {
            float b = (i < 896) ? bq[(size_t)layer * 896 + i]
                    : (i < 1024) ? bk[(size_t)layer * 128 + i - 896]
                                 : bv[(size_t)layer * 128 + i - 1024];
            bqkv[i] = b;
        }
    }
}

// past-cache copy (f32 cache, proven r5)
__device__ __forceinline__ void cache_copy_body(
    const float* __restrict__ kc32, const float* __restrict__ vc32, int layer,
    __half* __restrict__ Ka, __half* __restrict__ Vt, int p, int lt)
{
    const int kvh = lt >> 6, d = lt & 63;
    const size_t idx = (((size_t)layer * NKV + kvh) * MAXS + p) * HD + d;
    Ka[((size_t)kvh * ENDS + p) * HD + d] = __float2half(kc32[idx]);
    Vt[((size_t)kvh * HD + d) * ENDS + p] = __float2half(vc32[idx]);
}

// legacy-only rope (fallback path)
__device__ __forceinline__ void ropekv_body(
    const float* __restrict__ part, const float* __restrict__ bias,
    const float* __restrict__ cosb, const float* __restrict__ sinb,
    const float* __restrict__ injm, const float* __restrict__ injk,
    const float* __restrict__ injv, const float* __restrict__ kc32,
    const float* __restrict__ vc32, int layer, int nsplit,
    __half* __restrict__ qr, __half* __restrict__ Ka, __half* __restrict__ Vt,
    int p, int lt)
{
    const int kvh = lt >> 6, d = lt & 63;
    if (p < PAST) { cache_copy_body(kc32, vc32, layer, Ka, Vt, p, lt); return; }
    const int pn = p - PAST;
    const float inj = injm[0], nrm = 1.f - inj;
    const float* rb = part + (size_t)pn * 1152;
    const size_t sst = (size_t)QLEN * 1152;
    auto rsum = [&](int c) {
        float x = bias[c];
        for (int s = 0; s < nsplit; s++) x += rb[(size_t)s * sst + c];
        return x;
    };
    for (int idx = lt; idx < NQ * HD; idx += 128) {
        const int dd = idx & 63;
        float x = rsum(idx);
        int pc = (dd < 32) ? idx + 32 : idx - 32;
        float pv = rsum(pc);
        if (dd < 32) pv = -pv;
        float rv = x * cosb[pn * HD + dd] + pv * sinb[pn * HD + dd];
        qr[((size_t)(idx >> 6) * QLEN + pn) * HD + dd] = __float2half(rv);
    }
    {
        const int c = NQ * HD + lt;
        float x = rsum(c);
        int pc = (d < 32) ? c + 32 : c - 32;
        float pv = rsum(pc);
        if (d < 32) pv = -pv;
        float rv = x * cosb[pn * HD + d] + pv * sinb[pn * HD + d];
        float kn = nrm * rv + inj * injk[(((size_t)layer * NKV + kvh) * QLEN + pn) * HD + d];
        Ka[((size_t)kvh * ENDS + PAST + pn) * HD + d] = __float2half(kn);
        const int cv = NQ * HD + NKV * HD + lt;
        float vv = rsum(cv);
        float vn = nrm * vv + inj * injv[(((size_t)layer * NKV + kvh) * QLEN + pn) * HD + d];
        Vt[((size_t)kvh * HD + d) * ENDS + PAST + pn] = __float2half(vn);
    }
}

__device__ __forceinline__ int sswz(int row, int col) {
    return row * 1032 + (col ^ ((row & 7) << 3));
}

__device__ __forceinline__ void attn_body(
    const __half* __restrict__ qr, const __half* __restrict__ Ka,
    const __half* __restrict__ Vt, const float* __restrict__ mask,
    __half* __restrict__ ob, int q0, int h, int t, __half* S, float* rowinv)
{
    const int kv = h / GQ;
    const int lane = t & 63, w = t >> 6;
    const int la = lane & 15, kg = lane >> 4;

    const f16x8* qp = (const f16x8*)&qr[((size_t)h * QLEN + q0 + la) * HD + kg * 8];
    const f16x8 qa0 = qp[0], qa1 = qp[4];
    __syncthreads();

    for (int kb = 0; kb < 256; kb += 16) {
        const int key = w * 256 + kb + la;
        const f16x8* kp = (const f16x8*)&Ka[((size_t)kv * ENDS + key) * HD + kg * 8];
        f32x4 s4 = {0.f, 0.f, 0.f, 0.f};
        s4 = __builtin_amdgcn_mfma_f32_16x16x32_f16(qa0, kp[0], s4, 0, 0, 0);
        s4 = __builtin_amdgcn_mfma_f32_16x16x32_f16(qa1, kp[4], s4, 0, 0, 0);
#pragma unroll
        for (int r = 0; r < 4; r++) {
            const int row = kg * 4 + r;
            float sv = s4[r] * ATT_SCALE + mask[(size_t)(q0 + row) * ENDS + key];
            S[sswz(row, key)] = __float2half(sv);
        }
    }
    __syncthreads();
    {
        const int row = w * 4 + kg;
        float mx = -1e30f;
        for (int j = 0; j < 64; j++)
            mx = fmaxf(mx, __half2float(S[sswz(row, la + 16 * j)]));
        for (int o = 1; o < 16; o <<= 1) mx = fmaxf(mx, __shfl_xor(mx, o));
        float sum = 0.f;
        for (int j = 0; j < 64; j++) {
            const int idx = sswz(row, la + 16 * j);
            float e = __expf(__half2float(S[idx]) - mx);
            S[idx] = __float2half(e);
            sum += e;
        }
        for (int o = 1; o < 16; o <<= 1) sum += __shfl_xor(sum, o);
        if (la == 0) rowinv[row] = 1.f / sum;
    }
    __syncthreads();
    {
        const int d = 16 * w + la;
        const __half* vrow = &Vt[((size_t)kv * HD + d) * ENDS];
        f32x4 acc = {0.f, 0.f, 0.f, 0.f};
        for (int ks = 0; ks < ENDS; ks += 32) {
            f16x8 pa = *(const f16x8*)&S[sswz(la, ks + kg * 8)];
            f16x8 vb = *(const f16x8*)&vrow[ks + kg * 8];
            acc = __builtin_amdgcn_mfma_f32_16x16x32_f16(pa, vb, acc, 0, 0, 0);
        }
#pragma unroll
        for (int r = 0; r < 4; r++) {
            const int qrow = kg * 4 + r;
            ob[(size_t)(q0 + qrow) * (NQ * HD) + h * HD + d] =
                __float2half(acc[r] * rowinv[qrow]);
        }
    }
    __syncthreads();
}

__device__ inline void cvt_store(float* p, float v)  { *p = v; }
__device__ inline void cvt_store(__half* p, float v) { *p = __float2half(v); }

template <typename OUT>
__device__ __forceinline__ void rms_body(
    float* __restrict__ h, const float* __restrict__ parts, int nparts,
    const float* __restrict__ w, OUT* __restrict__ out, int m, int t,
    float* red, float scale)
{
    float loc[4];
    float ss = 0.f;
    int r = 0;
    for (int i = t; i < DMODEL; i += 256, r++) {
        float x = h[(size_t)m * DMODEL + i];
        for (int s = 0; s < nparts; s++)
            x += parts[(size_t)s * QLEN * DMODEL + (size_t)m * DMODEL + i];
        loc[r] = x;
        if (nparts) h[(size_t)m * DMODEL + i] = x;
        ss += x * x;
    }
    for (int o = 32; o; o >>= 1) ss += __shfl_xor(ss, o);
    if ((t & 63) == 0) red[t >> 6] = ss;
    __syncthreads();
    float rs = rsqrtf((red[0] + red[1] + red[2] + red[3]) / (float)DMODEL + RMSEPS);
    r = 0;
    for (int i = t; i < DMODEL; i += 256, r++)
        cvt_store(&out[(size_t)m * DMODEL + i], loc[r] * rs * w[i] * scale);
    __syncthreads();
}

// ---------------------------------------------------------------------------
// mega kernel: 7 phases/layer; prep(l+1) spread; cache_copy(l+1) in phase D.
// ---------------------------------------------------------------------------
struct P22 {
    const float *hidden, *cosb, *sinb, *mask, *injm, *injk, *injv, *kc32, *vc32;
    const float *Wq, *bq, *Wk, *bk, *Wv, *bv, *Wo, *ln1, *ln2, *Wg, *Wu, *Wd, *finw;
    float *h; __half *xn, *qr, *Ka, *Vt, *ob, *act; float *BIGR;
    float *bqkv0, *bqkv1;
    __half *wq0, *wo0, *wgu0, *wd0, *wq1, *wo1, *wgu1, *wd1;
    float *outF;
};

// prep chunks (sum = 3640)
#define PC_B 1200
#define PC_C 200
#define PC_D 800
#define PC_F 1000
#define PC_G 440
#define PB_B 0
#define PB_C 1200
#define PB_D 1400
#define PB_F 2200
#define PB_G 3200

__global__ __launch_bounds__(256) void mega_kernel(P22 P)
{
    __shared__ SmemU sm;
    cg::grid_group gg = cg::this_grid();
    const int nb = gridDim.x, bid = blockIdx.x, t = threadIdx.x;
    const float inj = P.injm[0];

    for (int j = bid; j < 1792; j += nb) {
        int i = j * 256 + t;
        if (i < QLEN * DMODEL) P.h[i] = P.hidden[i];
    }
    for (int j = bid; j < 256; j += nb)
        cache_copy_body(P.kc32, P.vc32, 0, P.Ka, P.Vt, j * 2 + (t >> 7), t & 127);
    for (int j = bid; j < 3640; j += nb)
        prep_dispatch(P.Wq, P.Wk, P.Wv, P.Wo, P.Wg, P.Wu, P.Wd, P.bq, P.bk, P.bv,
                      0, j, t, sm.p.T, P.wq0, P.wo0, P.wgu0, P.wd0, P.bqkv0);
    gg.sync();

    for (int l = 0; l < NLAYER; l++) {
        const int pb = l & 1;
        const __half* wq  = pb ? P.wq1  : P.wq0;
        const __half* wo  = pb ? P.wo1  : P.wo0;
        const __half* wgu = pb ? P.wgu1 : P.wgu0;
        const __half* wd  = pb ? P.wd1  : P.wd0;
        const float*  bqk = pb ? P.bqkv1 : P.bqkv0;
        const bool hasN = (l + 1 < NLAYER);
        __half* nwq  = pb ? P.wq0  : P.wq1;
        __half* nwo  = pb ? P.wo0  : P.wo1;
        __half* nwgu = pb ? P.wgu0 : P.wgu1;
        __half* nwd  = pb ? P.wd0  : P.wd1;
        float*  nbq  = pb ? P.bqkv0 : P.bqkv1;
        #define PREPN(idx) prep_dispatch(P.Wq, P.Wk, P.Wv, P.Wo, P.Wg, P.Wu, P.Wd, \
            P.bq, P.bk, P.bv, l + 1, (idx), t, sm.p.T, nwq, nwo, nwgu, nwd, nbq)

        // A: rms1 (+ D(l-1) split-19 reduce)
        for (int j = bid; j < QLEN; j += nb)
            rms_body<__half>(P.h, l ? P.BIGR : nullptr, l ? 19 : 0,
                             P.ln1 + (size_t)l * DMODEL, P.xn, j, t, sm.r.red, 1.f);
        gg.sync();

        // B: QKV gemm fused rope (36, K=896 -> 14 iters) + prep
        for (int j = bid; j < 36 + (hasN ? PC_B : 0); j += nb) {
            if (j < 36)
                gemm_qkv_body(P.xn, wq, bqk, P.cosb, P.sinb, inj, P.injk, P.injv,
                              P.qr, P.Ka, P.Vt, l, j % 9, j / 9, t, sm.g.As, sm.g.Bs);
            else PREPN(PB_B + j - 36);
        }
        gg.sync();

        // C: attention (448) + prep
        for (int j = bid; j < 448 + (hasN ? PC_C : 0); j += nb) {
            if (j < 448)
                attn_body(P.qr, P.Ka, P.Vt, P.mask, P.ob, (j & 31) * 16, j >> 5, t,
                          sm.a.S, sm.a.rowinv);
            else PREPN(PB_C + j - 448);
        }
        gg.sync();

        // D: O gemm split-7 (196, 2 iters) + cache_copy(l+1) (256) + prep
        for (int j = bid; j < 452 + (hasN ? PC_D : 0); j += nb) {
            if (j < 196) {
                int z = j / 28, r = j % 28;
                gemm_body(P.ob, DMODEL, wo, DMODEL, P.BIGR, nullptr, DMODEL, 128, 0,
                          r % 7, r / 7, z, t, sm.g.As, sm.g.Bs);
            } else if (j < 452) {
                if (hasN) cache_copy_body(P.kc32, P.vc32, l + 1, P.Ka, P.Vt,
                                          (j - 196) * 2 + (t >> 7), t & 127);
            } else PREPN(PB_D + j - 452);
        }
        gg.sync();

        // E: rms2 (nparts=7)
        for (int j = bid; j < QLEN; j += nb)
            rms_body<__half>(P.h, P.BIGR, 7, P.ln2 + (size_t)l * DMODEL, P.xn,
                             j, t, sm.r.red, 1.f);
        gg.sync();

        // F: GU gemm fused silu (304, 14 iters) + prep
        for (int j = bid; j < 304 + (hasN ? PC_F : 0); j += nb) {
            if (j < 304)
                gemm_body(P.xn, DMODEL, wgu, DMODEL, nullptr, P.act, 2 * FF, 896, 1,
                          j % 76, j / 76, 0, t, sm.g.As, sm.g.Bs);
            else PREPN(PB_F + j - 304);
        }
        gg.sync();

        // G: D gemm split-19 (532, 4 iters) + prep
        for (int j = bid; j < 532 + (hasN ? PC_G : 0); j += nb) {
            if (j < 532) {
                int z = j / 28, r = j % 28;
                gemm_body(P.act, FF, wd, FF, P.BIGR, nullptr, DMODEL, 256, 0,
                          r % 7, r / 7, z, t, sm.g.As, sm.g.Bs);
            } else PREPN(PB_G + j - 532);
        }
        gg.sync();
        #undef PREPN
    }
    for (int j = bid; j < QLEN; j += nb)
        rms_body<float>(P.h, P.BIGR, 19, P.finw, P.outF, j, t, sm.r.red, 1.f);
}

// ---------------------------------------------------------------------------
// legacy fallback wrappers
// ---------------------------------------------------------------------------
__global__ __launch_bounds__(256) void init_kernel(
    const float* __restrict__ hidden, float* __restrict__ h)
{
    const int idx = blockIdx.x * 256 + threadIdx.x;
    if (idx < QLEN * DMODEL) h[idx] = hidden[idx];
}

__global__ __launch_bounds__(256) void prep_all(
    const float* Wq, const float* Wk, const float* Wv, const float* Wo,
    const float* Wg, const float* Wu, const float* Wd,
    const float* bq, const float* bk, const float* bv, int layer,
    __half* wqkv, __half* wo, __half* wgu, __half* wd, float* bqkv)
{
    __shared__ float T[32][129];
    prep_dispatch(Wq, Wk, Wv, Wo, Wg, Wu, Wd, bq, bk, bv, layer, blockIdx.x,
                  threadIdx.x, T, wqkv, wo, wgu, wd, bqkv);
}

__global__ __launch_bounds__(256) void gemm128(
    const __half* A, int lda, const __half* B, int ldb,
    float* outP, __half* actP, int N, int Kps, int mode)
{
    __shared__ SmemU sm;
    gemm_body(A, lda, B, ldb, outP, actP, N, Kps, mode,
              blockIdx.x, blockIdx.y, blockIdx.z, threadIdx.x, sm.g.As, sm.g.Bs);
}

__global__ __launch_bounds__(128) void ropekv_kernel(
    const float* part, const float* bias, const float* cosb, const float* sinb,
    const float* injm, const float* injk, const float* injv,
    const float* kc32, const float* vc32, int layer, int nsplit,
    __half* qr, __half* Ka, __half* Vt)
{
    ropekv_body(part, bias, cosb, sinb, injm, injk, injv, kc32, vc32,
                layer, nsplit, qr, Ka, Vt, blockIdx.x, threadIdx.x);
}

__global__ __launch_bounds__(256) void attn_mfma(
    const __half* qr, const __half* Ka, const __half* Vt, const float* mask, __half* ob)
{
    __shared__ SmemU sm;
    attn_body(qr, Ka, Vt, mask, ob, blockIdx.x * 16, blockIdx.y, threadIdx.x,
              sm.a.S, sm.a.rowinv);
}

template <typename OUT>
__global__ __launch_bounds__(256) void rms_kernel(
    float* h, const float* parts, int nparts, const float* w, OUT* out)
{
    __shared__ float red[4];
    rms_body<OUT>(h, parts, nparts, w, out, blockIdx.x, threadIdx.x, red, 1.f);
}

// ---------------------------------------------------------------------------
extern "C" void kernel_launch(void* const* d_in, const int* in_sizes, int n_in,
                              void* d_out, int out_size, void* d_ws, size_t ws_size,
                              hipStream_t stream)
{
    const float*  hidden = (const float*)d_in[0];
    const float*  cosb   = (const float*)d_in[1];
    const float*  sinb   = (const float*)d_in[2];
    const float*  mask   = (const float*)d_in[3];
    const float*  injm   = (const float*)d_in[4];
    const float*  injk   = (const float*)d_in[5];
    const float*  injv   = (const float*)d_in[6];
    const float*  kc32   = (const float*)d_in[7];   // f32 (harness upcast, proven r5)
    const float*  vc32   = (const float*)d_in[8];
    const float*  Wq     = (const float*)d_in[9];
    const float*  bq     = (const float*)d_in[10];
    const float*  Wk     = (const float*)d_in[11];
    const float*  bk     = (const float*)d_in[12];
    const float*  Wv     = (const float*)d_in[13];
    const float*  bv     = (const float*)d_in[14];
    const float*  Wo     = (const float*)d_in[15];
    const float*  ln1    = (const float*)d_in[16];
    const float*  ln2    = (const float*)d_in[17];
    const float*  Wg     = (const float*)d_in[18];
    const float*  Wu     = (const float*)d_in[19];
    const float*  Wd     = (const float*)d_in[20];
    const float*  finw   = (const float*)d_in[21];

    bool size_ok = (n_in == 22) &&
        in_sizes[0] == 458752 && in_sizes[1] == 32768 && in_sizes[3] == 524288 &&
        in_sizes[4] == 1 && in_sizes[5] == 1310720 && in_sizes[7] == 5242880 &&
        in_sizes[9] == 16056320 && in_sizes[10] == 17920 && in_sizes[11] == 2293760 &&
        in_sizes[15] == 16056320 && in_sizes[16] == 17920 && in_sizes[18] == 87162880 &&
        in_sizes[20] == 87162880 && in_sizes[21] == 896;
    if (!size_ok) { hipMemsetAsync(d_out, 0x42, (size_t)out_size * 4, stream); return; }

    char* ws = (char*)d_ws;
    size_t off = 0;
    auto alloc = [&](size_t bytes) { void* p = ws + off; off += (bytes + 255) & ~255ull; return p; };
    float*  bqkv0 = (float*)alloc(1152 * 4);
    float*  bqkv1 = (float*)alloc(1152 * 4);
    float*  h     = (float*)alloc((size_t)QLEN * DMODEL * 4);
    __half* xn    = (__half*)alloc((size_t)QLEN * DMODEL * 2);
    __half* qr    = (__half*)alloc((size_t)NQ * QLEN * HD * 2);
    __half* Ka    = (__half*)alloc((size_t)NKV * ENDS * HD * 2);
    __half* Vt    = (__half*)alloc((size_t)NKV * ENDS * HD * 2);
    __half* ob    = (__half*)alloc((size_t)QLEN * NQ * HD * 2);
    __half* act   = (__half*)alloc((size_t)QLEN * FF * 2);
    float*  BIGR  = (float*)alloc(19ull * QLEN * DMODEL * 4);
    __half* wq0   = (__half*)alloc(2064384);
    __half* wo0   = (__half*)alloc(1605632);
    __half* wgu0  = (__half*)alloc(17432576);
    __half* wd0   = (__half*)alloc(8716288);
    const size_t NEED_LEGACY = off;
    __half* wq1   = (__half*)alloc(2064384);
    __half* wo1   = (__half*)alloc(1605632);
    __half* wgu1  = (__half*)alloc(17432576);
    __half* wd1   = (__half*)alloc(8716288);
    const size_t NEED_MEGA = off;

    if (ws_size < NEED_LEGACY) {
        hipMemsetAsync(d_out, 0, (size_t)out_size * 4, stream);
        return;
    }

    bool mega_ok = (ws_size >= NEED_MEGA);
    if (mega_ok) {
        int maxB = 0;
        hipError_t e = hipOccupancyMaxActiveBlocksPerMultiprocessor(
            &maxB, reinterpret_cast<const void*>(&mega_kernel), 256, 0);
        if (e != hipSuccess || maxB < 1) mega_ok = false;
        if (mega_ok) {
            int grid = maxB * 256;
            if (grid > 512) grid = 512;
            P22 Pv = { hidden, cosb, sinb, mask, injm, injk, injv, kc32, vc32,
                       Wq, bq, Wk, bk, Wv, bv, Wo, ln1, ln2, Wg, Wu, Wd, finw,
                       h, xn, qr, Ka, Vt, ob, act, BIGR, bqkv0, bqkv1,
                       wq0, wo0, wgu0, wd0, wq1, wo1, wgu1, wd1, (float*)d_out };
            void* args[] = { (void*)&Pv };
            hipError_t le = hipLaunchCooperativeKernel(
                reinterpret_cast<const void*>(&mega_kernel),
                dim3(grid), dim3(256), args, 0, stream);
            if (le == hipSuccess) return;
            mega_ok = false;
        }
    }

    // ---- legacy path (BK=64-compatible splits) ----
    init_kernel<<<1792, 256, 0, stream>>>(hidden, h);
    for (int l = 0; l < NLAYER; l++) {
        prep_all<<<3640, 256, 0, stream>>>(Wq, Wk, Wv, Wo, Wg, Wu, Wd, bq, bk, bv, l,
                                           wq0, wo0, wgu0, wd0, bqkv0);
        rms_kernel<__half><<<QLEN, 256, 0, stream>>>(h, l ? BIGR : nullptr, l ? 19 : 0,
                                                     ln1 + (size_t)l * DMODEL, xn);
        gemm128<<<dim3(9, 4, 2), 256, 0, stream>>>(xn, DMODEL, wq0, DMODEL, BIGR, nullptr, 1152, 448, 0);
        ropekv_kernel<<<ENDS, 128, 0, stream>>>(BIGR, bqkv0, cosb, sinb, injm, injk, injv,
                                                kc32, vc32, l, 2, qr, Ka, Vt);
        attn_mfma<<<dim3(32, 14), 256, 0, stream>>>(qr, Ka, Vt, mask, ob);
        gemm128<<<dim3(7, 4, 7), 256, 0, stream>>>(ob, DMODEL, wo0, DMODEL, BIGR, nullptr, DMODEL, 128, 0);
        rms_kernel<__half><<<QLEN, 256, 0, stream>>>(h, BIGR, 7, ln2 + (size_t)l * DMODEL, xn);
        gemm128<<<dim3(76, 4, 1), 256, 0, stream>>>(xn, DMODEL, wgu0, DMODEL, nullptr, act, 2 * FF, 896, 1);
        gemm128<<<dim3(7, 4, 19), 256, 0, stream>>>(act, FF, wd0, FF, BIGR, nullptr, DMODEL, 256, 0);
    }
    rms_kernel<float><<<QLEN, 256, 0, stream>>>(h, BIGR, 19, finw, (float*)d_out);
}